// Round 3
// baseline (1632.536 us; speedup 1.0000x reference)
//
#include <hip/hip_runtime.h>
#include <hip/hip_bf16.h>
#include <cstddef>

#define T_SEQ 512
#define BATCH 256
#define RTOT (BATCH * T_SEQ) /* 131072 rows */

__device__ __forceinline__ float fsigmoid(float x) {
    return 1.0f / (1.0f + __expf(-x));
}
__device__ __forceinline__ float ftanh(float x) {
    // tanh(x) = 1 - 2/(exp(2x)+1); saturates correctly at +-inf
    return 1.0f - 2.0f / (__expf(2.0f * x) + 1.0f);
}

// ---------------------------------------------------------------------------
// Input projection: xp[r, 0:192] = x[r, :] @ W + bi   for both directions.
// One block = 32 rows x 384 cols (f+b). X staged transposed in LDS so the
// inner loop reads 16B-aligned float4 broadcasts.
// ---------------------------------------------------------------------------
template <int DIN, bool EMBED>
__global__ __launch_bounds__(192) void proj_kernel(
    const float* __restrict__ X, const int* __restrict__ tokens,
    const float* __restrict__ emb,
    const float* __restrict__ Wf, const float* __restrict__ bf_,
    const float* __restrict__ Wb, const float* __restrict__ bb_,
    float* __restrict__ xpf, float* __restrict__ xpb)
{
    constexpr int ROWS = 32;
    constexpr int PAD = 36; // row stride 144B: 16B-aligned float4 reads
    __shared__ __align__(16) float xt[DIN][PAD];
    const int r0 = blockIdx.x * ROWS;
    const int tid = threadIdx.x;

    for (int e = tid; e < ROWS * DIN; e += 192) {
        const int row = e / DIN;
        const int i = e % DIN;
        float v;
        if (EMBED) {
            v = emb[(size_t)tokens[r0 + row] * 64 + i];
        } else {
            v = X[(size_t)(r0 + row) * DIN + i];
        }
        xt[i][row] = v;
    }
    __syncthreads();

    const int col = tid; // 0..191
    #pragma unroll
    for (int d = 0; d < 2; d++) {
        const float* __restrict__ W = d ? Wb : Wf;
        const float* __restrict__ bi = d ? bb_ : bf_;
        float* __restrict__ outp = d ? xpb : xpf;
        float acc[ROWS];
        const float b0 = bi[col];
        #pragma unroll
        for (int r = 0; r < ROWS; r++) acc[r] = b0;
        #pragma unroll 4
        for (int i = 0; i < DIN; i++) {
            const float w = W[i * 192 + col]; // coalesced, L2-hot
            #pragma unroll
            for (int r = 0; r < ROWS; r += 4) {
                const float4 x4 = *(const float4*)&xt[i][r];
                acc[r + 0] = fmaf(x4.x, w, acc[r + 0]);
                acc[r + 1] = fmaf(x4.y, w, acc[r + 1]);
                acc[r + 2] = fmaf(x4.z, w, acc[r + 2]);
                acc[r + 3] = fmaf(x4.w, w, acc[r + 3]);
            }
        }
        #pragma unroll
        for (int r = 0; r < ROWS; r++) {
            outp[(size_t)(r0 + r) * 192 + col] = acc[r];
        }
    }
}

// ---------------------------------------------------------------------------
// Barrier-free recurrent scan: ONE WAVE (64 threads) per (batch, direction)
// chain. Lane j owns ALL THREE gate columns j (z_j, r_j, hh_j) and state h_j:
// the state update is lane-local; only the h broadcast for the next mat-vec
// crosses lanes, via LDS (ds_write then broadcast ds_read — LDS ops from one
// wave complete in order, and with a 64-thread workgroup the backend elides
// s_barrier, so NO barriers in the 512-step loop).
// Weights: lane j holds Wh[:,j], Wh[:,64+j], Wh[:,128+j] in 192 VGPRs.
// Tokens staged once as a float mask in LDS. xp streamed with distance-2
// prefetch (HBM latency ~900cyc > 1 step).
// ---------------------------------------------------------------------------
__global__ __launch_bounds__(64, 1) void gru_scan_w64(
    const float* __restrict__ xpf, const float* __restrict__ xpb,
    const float* __restrict__ whf, const float* __restrict__ whb,
    const float* __restrict__ bbf, const float* __restrict__ bbb,
    const int* __restrict__ tokens,
    float* __restrict__ y,        // [RTOT,128] or nullptr
    float* __restrict__ hfinal)   // [BATCH,128] or nullptr
{
    const int chain = blockIdx.x; // 0..511
    const int b = chain >> 1;
    const int dir = chain & 1;
    const float* __restrict__ xp = dir ? xpb : xpf;
    const float* __restrict__ wh = dir ? whb : whf;
    const float* __restrict__ bbv = dir ? bbb : bbf;
    const int j = threadIdx.x; // 0..63

    float wz[64], wr[64], wc[64];
    #pragma unroll
    for (int i = 0; i < 64; i++) {
        wz[i] = wh[i * 192 + j];
        wr[i] = wh[i * 192 + 64 + j];
        wc[i] = wh[i * 192 + 128 + j];
    }
    const float bhz = bbv[192 + j];       // recurrent bias row (bb[1])
    const float bhr = bbv[192 + 64 + j];
    const float bhc = bbv[192 + 128 + j];

    __shared__ __align__(16) float h_lds[64];
    __shared__ float m_lds[T_SEQ];
    const size_t base = (size_t)b * T_SEQ;
    #pragma unroll
    for (int u = 0; u < T_SEQ / 64; u++) {
        const int tk = tokens[base + u * 64 + j];
        m_lds[u * 64 + j] = (tk > 0) ? 1.0f : 0.0f;
    }
    h_lds[j] = 0.0f;
    float h = 0.0f;
    __syncthreads(); // once, outside the loop

    const int t0 = dir ? (T_SEQ - 1) : 0;
    const int st = dir ? -1 : 1;
    const float* xrow = xp + (base + t0) * 192; // row for current t
    float xz0 = xrow[j], xr0 = xrow[64 + j], xc0 = xrow[128 + j];
    const float* xrow1 = xrow + st * 192;
    float xz1 = xrow1[j], xr1 = xrow1[64 + j], xc1 = xrow1[128 + j];

    float* yp = y ? (y + (base + t0) * 128 + (dir << 6) + j) : nullptr;
    const ptrdiff_t ystep = (ptrdiff_t)st * 128;
    int mt = t0;

    #pragma unroll 2
    for (int t = 0; t < T_SEQ; t++) {
        // distance-2 prefetch (guarded; reuses current row on the tail)
        const float* rp = (t + 2 < T_SEQ) ? (xrow + 2 * st * 192) : xrow;
        const float pz = rp[j], pr = rp[64 + j], pc = rp[128 + j];
        const float m = m_lds[mt]; // uniform addr -> LDS broadcast

        float az = bhz, ar = bhr, ac = bhc;
        #pragma unroll
        for (int i = 0; i < 64; i += 4) {
            const float4 h4 = *(const float4*)&h_lds[i]; // broadcast read
            az = fmaf(h4.x, wz[i + 0], az);
            ar = fmaf(h4.x, wr[i + 0], ar);
            ac = fmaf(h4.x, wc[i + 0], ac);
            az = fmaf(h4.y, wz[i + 1], az);
            ar = fmaf(h4.y, wr[i + 1], ar);
            ac = fmaf(h4.y, wc[i + 1], ac);
            az = fmaf(h4.z, wz[i + 2], az);
            ar = fmaf(h4.z, wr[i + 2], ar);
            ac = fmaf(h4.z, wc[i + 2], ac);
            az = fmaf(h4.w, wz[i + 3], az);
            ar = fmaf(h4.w, wr[i + 3], ar);
            ac = fmaf(h4.w, wc[i + 3], ac);
        }
        const float z  = fsigmoid(xz0 + az);
        const float r  = fsigmoid(xr0 + ar);
        const float hh = ftanh(xc0 + r * ac);
        const float hnew = z * h + (1.0f - z) * hh;
        h = fmaf(m, hnew - h, h);     // masked carry (m in {0,1})
        if (yp) { *yp = h; yp += ystep; }
        h_lds[j] = h; // no barrier: single wave, DS pipe is in-order
        xz0 = xz1; xr0 = xr1; xc0 = xc1;
        xz1 = pz;  xr1 = pr;  xc1 = pc;
        xrow += st * 192;
        mt += st;
    }
    if (hfinal) hfinal[b * 128 + (dir << 6) + j] = h;
}

// ---------------------------------------------------------------------------
// MLP head: one block (1 wave) per batch row.
// ---------------------------------------------------------------------------
__global__ __launch_bounds__(64) void mlp_kernel(
    const float* __restrict__ hcat, // [BATCH,128]
    const float* __restrict__ wd1, const float* __restrict__ bd1,
    const float* __restrict__ wd2, const float* __restrict__ bd2,
    const float* __restrict__ wd3, const float* __restrict__ bd3,
    const float* __restrict__ wo, const float* __restrict__ bo,
    float* __restrict__ outp)       // [BATCH,28]
{
    const int b = blockIdx.x;
    const int j = threadIdx.x; // 0..63
    __shared__ float x0[128];
    __shared__ float x1[64];
    x0[j] = hcat[b * 128 + j];
    x0[j + 64] = hcat[b * 128 + 64 + j];
    __syncthreads();
    float a = bd1[j];
    #pragma unroll 4
    for (int i = 0; i < 128; i++) a = fmaf(x0[i], wd1[i * 64 + j], a);
    a = fmaxf(a, 0.0f);
    x1[j] = a;
    __syncthreads();
    float a2 = bd2[j];
    #pragma unroll 4
    for (int i = 0; i < 64; i++) a2 = fmaf(x1[i], wd2[i * 64 + j], a2);
    a2 = fmaxf(a2, 0.0f);
    __syncthreads();
    x1[j] = a2;
    __syncthreads();
    float a3 = bd3[j];
    #pragma unroll 4
    for (int i = 0; i < 64; i++) a3 = fmaf(x1[i], wd3[i * 64 + j], a3);
    a3 = fmaxf(a3, 0.0f);
    __syncthreads();
    x1[j] = a3;
    __syncthreads();
    if (j < 28) {
        float o = bo[j];
        #pragma unroll 4
        for (int i = 0; i < 64; i++) o = fmaf(x1[i], wo[i * 28 + j], o);
        outp[b * 28 + j] = fsigmoid(o);
    }
}

// ---------------------------------------------------------------------------
extern "C" void kernel_launch(void* const* d_in, const int* in_sizes, int n_in,
                              void* d_out, int out_size, void* d_ws, size_t ws_size,
                              hipStream_t stream)
{
    const int* tokens  = (const int*)d_in[0];
    const float* emb   = (const float*)d_in[1];
    const float* wi1f  = (const float*)d_in[2];
    const float* wh1f  = (const float*)d_in[3];
    const float* bb1f  = (const float*)d_in[4];
    const float* wi1b  = (const float*)d_in[5];
    const float* wh1b  = (const float*)d_in[6];
    const float* bb1b  = (const float*)d_in[7];
    const float* wi2f  = (const float*)d_in[8];
    const float* wh2f  = (const float*)d_in[9];
    const float* bb2f  = (const float*)d_in[10];
    const float* wi2b  = (const float*)d_in[11];
    const float* wh2b  = (const float*)d_in[12];
    const float* bb2b  = (const float*)d_in[13];
    const float* wi3f  = (const float*)d_in[14];
    const float* wh3f  = (const float*)d_in[15];
    const float* bb3f  = (const float*)d_in[16];
    const float* wi3b  = (const float*)d_in[17];
    const float* wh3b  = (const float*)d_in[18];
    const float* bb3b  = (const float*)d_in[19];
    const float* wd1   = (const float*)d_in[20];
    const float* bd1   = (const float*)d_in[21];
    const float* wd2   = (const float*)d_in[22];
    const float* bd2   = (const float*)d_in[23];
    const float* wd3   = (const float*)d_in[24];
    const float* bd3   = (const float*)d_in[25];
    const float* wo    = (const float*)d_in[26];
    const float* bo    = (const float*)d_in[27];

    // Workspace layout (all fp32) — total EXACTLY 256 MiB:
    //   y    : RTOT*128   67,108,864 B
    //   xpf  : RTOT*192  100,663,296 B
    //   xpb  : RTOT*192  100,663,296 B
    //   hcat : aliased onto y (y is dead after proj3 reads it)
    float* y    = (float*)d_ws;
    float* xpf  = y + (size_t)RTOT * 128;
    float* xpb  = xpf + (size_t)RTOT * 192;
    float* hcat = y;

    const dim3 pb(192), pg(RTOT / 32);

    // Layer 1 (embedding fused into projection)
    proj_kernel<64, true><<<pg, pb, 0, stream>>>(nullptr, tokens, emb,
                                                 wi1f, bb1f, wi1b, bb1b, xpf, xpb);
    gru_scan_w64<<<512, 64, 0, stream>>>(xpf, xpb, wh1f, wh1b, bb1f, bb1b,
                                         tokens, y, nullptr);
    // Layer 2
    proj_kernel<128, false><<<pg, pb, 0, stream>>>(y, nullptr, nullptr,
                                                   wi2f, bb2f, wi2b, bb2b, xpf, xpb);
    gru_scan_w64<<<512, 64, 0, stream>>>(xpf, xpb, wh2f, wh2b, bb2f, bb2b,
                                         tokens, y, nullptr);
    // Layer 3 (final states only)
    proj_kernel<128, false><<<pg, pb, 0, stream>>>(y, nullptr, nullptr,
                                                   wi3f, bb3f, wi3b, bb3b, xpf, xpb);
    gru_scan_w64<<<512, 64, 0, stream>>>(xpf, xpb, wh3f, wh3b, bb3f, bb3b,
                                         tokens, nullptr, hcat);
    // Head
    mlp_kernel<<<256, 64, 0, stream>>>(hcat, wd1, bd1, wd2, bd2, wd3, bd3,
                                       wo, bo, (float*)d_out);
}